// Round 1
// baseline (557.823 us; speedup 1.0000x reference)
//
#include <hip/hip_runtime.h>

// ---------------------------------------------------------------------------
// CorefPairScorer: B=4, T=4096, D=768, N=256, HID=200 (padded to 224)
// Decomposition: h1(i,j) = relu(A[i] + Bv[j] + (emb_i*emb_j)@W1bot + b1)
//                h2 = relu(h1@W2 + b2); s = h2@W3 + b3; masked softmax rows.
// Heavy part done with mfma_f32_16x16x32_bf16 on 16x16 (i,j) tiles of the
// lower triangle (136 tiles/batch, 544 blocks, 512 threads = 8 waves).
// ---------------------------------------------------------------------------

#define NB 4
#define NN 256
#define DD 768
#define TT 4096
#define HP 224           // HID padded to 14*16
#define NTILES 14        // HP/16
#define KT1 24           // DD/32
#define KT2 7            // HP/32
#define TRI 136          // 16*17/2 tile-pairs per batch
#define JSTR 776         // embJ LDS row stride (bf16): 2-way bank alias (free)
#define HSTR 232         // h1 LDS row stride (bf16): 2-way bank alias (free)

typedef __attribute__((ext_vector_type(8))) short short8;
typedef __attribute__((ext_vector_type(4))) float f32x4;

union FragU { uint4 u; short8 s; };

__device__ __forceinline__ float bf2f(unsigned short x) {
    return __uint_as_float(((unsigned int)x) << 16);
}
__device__ __forceinline__ unsigned short f2bf(float f) {
    unsigned int u = __float_as_uint(f);
    u += 0x7fffu + ((u >> 16) & 1u);   // RNE
    return (unsigned short)(u >> 16);
}
// elementwise product of 2 packed bf16 pairs -> packed bf16 pair
__device__ __forceinline__ unsigned int bfmul2(unsigned int a, unsigned int b) {
    float a0 = __uint_as_float(a << 16);
    float a1 = __uint_as_float(a & 0xffff0000u);
    float b0 = __uint_as_float(b << 16);
    float b1 = __uint_as_float(b & 0xffff0000u);
    unsigned int r0 = f2bf(a0 * b0);
    unsigned int r1 = f2bf(a1 * b1);
    return r0 | (r1 << 16);
}

// ---------------------------------------------------------------------------
// K0: swizzle W1bot / W2 (padded, zero-filled) into MFMA B-fragment order:
//     buf[((kt*14+nt)*64 + lane)*8 + j] = W[kt*32 + 8*(lane>>4) + j][nt*16 + (lane&15)]
// ---------------------------------------------------------------------------
__global__ void prep_weights(const float* __restrict__ W1, const float* __restrict__ W2,
                             unsigned short* __restrict__ w1s, unsigned short* __restrict__ w2s) {
    int idx = blockIdx.x * 256 + threadIdx.x;
    const int N1 = KT1 * NTILES * 512;   // 172032
    const int N2 = KT2 * NTILES * 512;   // 50176
    if (idx < N1) {
        int j = idx & 7, lane = (idx >> 3) & 63, f = idx >> 9;
        int nt = f % NTILES, kt = f / NTILES;
        int k = kt * 32 + (lane >> 4) * 8 + j;     // 0..767
        int n = nt * 16 + (lane & 15);             // 0..223
        float v = (n < 200) ? W1[(size_t)(1536 + k) * 200 + n] : 0.f;
        w1s[idx] = f2bf(v);
    } else {
        int i2 = idx - N1;
        if (i2 < N2) {
            int j = i2 & 7, lane = (i2 >> 3) & 63, f = i2 >> 9;
            int nt = f % NTILES, kt = f / NTILES;
            int k = kt * 32 + (lane >> 4) * 8 + j; // 0..223
            int n = nt * 16 + (lane & 15);
            float v = (k < 200 && n < 200) ? W2[(size_t)k * 200 + n] : 0.f;
            w2s[i2] = f2bf(v);
        }
    }
}

// ---------------------------------------------------------------------------
// K1: gather + fp32->bf16 : emb[b][n][e] = event_embed[b][idx[b][n]][e]
// ---------------------------------------------------------------------------
__global__ void gather_embed(const float* __restrict__ ee, const int* __restrict__ eidx,
                             unsigned short* __restrict__ emb) {
    int b = blockIdx.x >> 8, n = blockIdx.x & 255;
    int t = eidx[b * NN + n];
    const float* src = ee + ((size_t)b * TT + t) * DD;
    unsigned short* dst = emb + ((size_t)b * NN + n) * DD;
    for (int e = threadIdx.x; e < DD; e += 256) dst[e] = f2bf(src[e]);
}

// ---------------------------------------------------------------------------
// K2: per-node terms A[i][h] = emb_i @ W1_top, Bv[j][h] = emb_j @ W1_mid
//     (fp32 VALU, 8 rows per block, padded cols 200..223 = 0)
// ---------------------------------------------------------------------------
__global__ __launch_bounds__(256) void node_terms(const unsigned short* __restrict__ emb,
                                                  const float* __restrict__ W1,
                                                  float* __restrict__ An, float* __restrict__ Bn) {
    int b = blockIdx.x >> 5;
    int n0 = (blockIdx.x & 31) << 3;
    __shared__ float se[8 * DD];
    for (int r2 = 0; r2 < 8; ++r2)
        for (int e = threadIdx.x; e < DD; e += 256)
            se[r2 * DD + e] = bf2f(emb[((size_t)b * NN + n0 + r2) * DD + e]);
    __syncthreads();
    int h = threadIdx.x;
    float accA[8] = {0, 0, 0, 0, 0, 0, 0, 0};
    float accB[8] = {0, 0, 0, 0, 0, 0, 0, 0};
    if (h < 200) {
        const float* w1t = W1 + h;
        const float* w1m = W1 + (size_t)768 * 200 + h;
        for (int e = 0; e < DD; ++e) {
            float wt = w1t[(size_t)e * 200];
            float wm = w1m[(size_t)e * 200];
#pragma unroll
            for (int r2 = 0; r2 < 8; ++r2) {
                float ev = se[r2 * DD + e];
                accA[r2] += ev * wt;
                accB[r2] += ev * wm;
            }
        }
    }
    if (h < HP) {
#pragma unroll
        for (int r2 = 0; r2 < 8; ++r2) {
            An[((size_t)b * NN + n0 + r2) * HP + h] = accA[r2];
            Bn[((size_t)b * NN + n0 + r2) * HP + h] = accB[r2];
        }
    }
}

// ---------------------------------------------------------------------------
// K3: fused pair MLP per 16x16 (i,j) tile. 512 threads = 8 waves.
//   wave w: mg = w>>1 (M-group: Mtiles 4mg..4mg+3), nh = w&1 (N-half: 7 ntiles)
//   phase1: acc[4][7] over K=768; A-frag generated on the fly (embI*embJ)
//   epilogue per half (128 pairs): + A[i] + Bv[j] + b1, relu -> bf16 LDS
//   phase2: acc2[2][7] over K=224 from LDS h1; phase3: dot W3 + shfl reduce
// ---------------------------------------------------------------------------
__global__ __launch_bounds__(512, 2) void pair_mlp(
    const unsigned short* __restrict__ emb,
    const unsigned short* __restrict__ w1s,
    const unsigned short* __restrict__ w2s,
    const float* __restrict__ An, const float* __restrict__ Bn,
    const float* __restrict__ b1, const float* __restrict__ b2,
    const float* __restrict__ W3, const float* __restrict__ b3,
    float* __restrict__ S) {
    int z = blockIdx.x;
    int b = z / TRI;
    int r = z % TRI;
    int ti = (int)((sqrtf(8.f * (float)r + 1.f) - 1.f) * 0.5f);
    while ((ti + 1) * (ti + 2) / 2 <= r) ++ti;
    while (ti * (ti + 1) / 2 > r) --ti;
    int tj = r - ti * (ti + 1) / 2;
    int i0 = ti << 4, j0 = tj << 4;

    int tid = threadIdx.x;
    int lane = tid & 63;
    int w = tid >> 6;
    int q = lane >> 4, c = lane & 15;
    int mg = w >> 1, nh = w & 1;

    __shared__ unsigned short sm[128 * HSTR];   // 59392 B (aliases embJ staging)
    __shared__ float sred[2][256];              // 2048 B

    // ---- stage embJ (16 rows x 768 bf16, stride 776) ----
    {
        const uint4* gJ = (const uint4*)(emb + ((size_t)b * NN + j0) * DD);
#pragma unroll
        for (int k = 0; k < 3; ++k) {
            int c2 = tid + 512 * k;            // 0..1535
            int row = c2 / 96, col = c2 - row * 96;
            uint4 v = gJ[row * 96 + col];
            *(uint4*)(&sm[row * JSTR + col * 8]) = v;
        }
    }
    __syncthreads();

    f32x4 acc[4][7];
#pragma unroll
    for (int t = 0; t < 4; ++t)
#pragma unroll
        for (int n = 0; n < 7; ++n)
            acc[t][n] = (f32x4){0.f, 0.f, 0.f, 0.f};

    const uint4* w1f = (const uint4*)w1s;
    const uint4* gI = (const uint4*)(emb + ((size_t)b * NN + i0 + mg * 4) * DD);

    // ---- phase 1 K-loop: K=768, 24 ktiles ----
    for (int kt = 0; kt < KT1; ++kt) {
        uint4 ej = *(const uint4*)(&sm[c * JSTR + kt * 32 + q * 8]);
        uint4 bfr[7];
#pragma unroll
        for (int n = 0; n < 7; ++n)
            bfr[n] = w1f[(kt * NTILES + nh * 7 + n) * 64 + lane];
#pragma unroll
        for (int t = 0; t < 4; ++t) {
            uint4 ei = gI[t * 96 + kt * 4 + q];   // wave-quad broadcast (L1)
            FragU a;
            a.u.x = bfmul2(ei.x, ej.x);
            a.u.y = bfmul2(ei.y, ej.y);
            a.u.z = bfmul2(ei.z, ej.z);
            a.u.w = bfmul2(ei.w, ej.w);
#pragma unroll
            for (int n = 0; n < 7; ++n) {
                FragU bb; bb.u = bfr[n];
                acc[t][n] = __builtin_amdgcn_mfma_f32_16x16x32_bf16(a.s, bb.s, acc[t][n], 0, 0, 0);
            }
        }
    }

    // per-lane col constants for phase 2/3
    float b2v[7], w3v[7];
#pragma unroll
    for (int n = 0; n < 7; ++n) {
        int h = ((nh * 7 + n) << 4) + c;
        b2v[n] = (h < 200) ? b2[h] : 0.f;
        w3v[n] = (h < 200) ? W3[h] : 0.f;
    }
    float b3val = b3[0];
    const uint4* w2f = (const uint4*)w2s;

    for (int half = 0; half < 2; ++half) {
        __syncthreads();   // sm free for this half's h1
        if ((mg >> 1) == half) {
#pragma unroll
            for (int t = 0; t < 4; ++t) {
                int tg = (mg << 2) + t;                    // global Mtile (== ii)
                int lt16 = (tg - (half << 3)) << 4;        // local row base
#pragma unroll
                for (int n = 0; n < 7; ++n) {
                    int h = ((nh * 7 + n) << 4) + c;
                    float aI = An[((size_t)b * NN + i0 + tg) * HP + h];
                    float base = aI + ((h < 200) ? b1[h] : 0.f);
#pragma unroll
                    for (int rr = 0; rr < 4; ++rr) {
                        float v = acc[t][n][rr] + base +
                                  Bn[((size_t)b * NN + j0 + q * 4 + rr) * HP + h];
                        v = fmaxf(v, 0.f);
                        sm[(lt16 + q * 4 + rr) * HSTR + h] = f2bf(v);
                    }
                }
            }
        }
        __syncthreads();

        // ---- phase 2: 128 pairs of this half, K=224 (7 ktiles) ----
        f32x4 acc2[2][7];
#pragma unroll
        for (int u = 0; u < 2; ++u)
#pragma unroll
            for (int n = 0; n < 7; ++n)
                acc2[u][n] = (f32x4){0.f, 0.f, 0.f, 0.f};

        for (int kk = 0; kk < KT2; ++kk) {
            uint4 bfr2[7];
#pragma unroll
            for (int n = 0; n < 7; ++n)
                bfr2[n] = w2f[(kk * NTILES + nh * 7 + n) * 64 + lane];
#pragma unroll
            for (int u = 0; u < 2; ++u) {
                int lt = mg * 2 + u;   // 0..7
                FragU a2;
                a2.u = *(const uint4*)(&sm[(lt * 16 + c) * HSTR + kk * 32 + q * 8]);
#pragma unroll
                for (int n = 0; n < 7; ++n) {
                    FragU bb; bb.u = bfr2[n];
                    acc2[u][n] = __builtin_amdgcn_mfma_f32_16x16x32_bf16(a2.s, bb.s, acc2[u][n], 0, 0, 0);
                }
            }
        }

        // ---- phase 3: s = relu(h2 + b2) . W3, reduce 16 cols via shfl ----
#pragma unroll
        for (int u = 0; u < 2; ++u) {
#pragma unroll
            for (int rr = 0; rr < 4; ++rr) {
                float part = 0.f;
#pragma unroll
                for (int n = 0; n < 7; ++n) {
                    float hv = fmaxf(acc2[u][n][rr] + b2v[n], 0.f);
                    part += hv * w3v[n];
                }
                part += __shfl_xor(part, 1);
                part += __shfl_xor(part, 2);
                part += __shfl_xor(part, 4);
                part += __shfl_xor(part, 8);
                if (c == 0) {
                    int p = (half << 7) + ((mg * 2 + u) << 4) + q * 4 + rr;
                    sred[nh][p] = part;
                }
            }
        }
    }
    __syncthreads();
    if (tid < 256) {
        int ii = tid >> 4, jj = tid & 15;
        float s = sred[0][tid] + sred[1][tid] + b3val;
        S[((size_t)b * NN + i0 + ii) * NN + j0 + jj] = s;
    }
}

// ---------------------------------------------------------------------------
// K4: masked softmax per row; diag logit = 0; invalid -> -1000
// ---------------------------------------------------------------------------
__global__ __launch_bounds__(256) void softmax_rows(const float* __restrict__ S,
                                                    float* __restrict__ out) {
    int b = blockIdx.x >> 8, i = blockIdx.x & 255;
    int j = threadIdx.x;
    int lane = j & 63, w = j >> 6;
    __shared__ float red[16];
    float x = (j < i) ? S[((size_t)b * NN + i) * NN + j] : ((j == i) ? 0.f : -1e30f);
    float m = x;
#pragma unroll
    for (int off = 32; off; off >>= 1) m = fmaxf(m, __shfl_xor(m, off));
    if (lane == 0) red[w] = m;
    __syncthreads();
    float mx = fmaxf(fmaxf(red[0], red[1]), fmaxf(red[2], red[3]));
    float e = (j <= i) ? __expf(x - mx) : 0.f;
    float s = e;
#pragma unroll
    for (int off = 32; off; off >>= 1) s += __shfl_xor(s, off);
    if (lane == 0) red[8 + w] = s;
    __syncthreads();
    float sum = red[8] + red[9] + red[10] + red[11];
    out[((size_t)b * NN + i) * NN + j] = (j <= i) ? (e / sum) : -1000.0f;
}

// ---------------------------------------------------------------------------
extern "C" void kernel_launch(void* const* d_in, const int* in_sizes, int n_in,
                              void* d_out, int out_size, void* d_ws, size_t ws_size,
                              hipStream_t stream) {
    const float* ee  = (const float*)d_in[0];
    const int*   eidx = (const int*)d_in[1];
    const float* W1  = (const float*)d_in[2];
    const float* b1  = (const float*)d_in[3];
    const float* W2  = (const float*)d_in[4];
    const float* b2  = (const float*)d_in[5];
    const float* W3  = (const float*)d_in[6];
    const float* b3  = (const float*)d_in[7];
    float* out = (float*)d_out;

    char* p = (char*)d_ws;
    unsigned short* emb = (unsigned short*)p; p += (size_t)NB * NN * DD * 2;        // 1.5 MB
    unsigned short* w1s = (unsigned short*)p; p += (size_t)KT1 * NTILES * 512 * 2;  // 336 KB
    unsigned short* w2s = (unsigned short*)p; p += (size_t)KT2 * NTILES * 512 * 2;  // 98 KB
    float* An = (float*)p; p += (size_t)NB * NN * HP * 4;                            // 896 KB
    float* Bn = (float*)p; p += (size_t)NB * NN * HP * 4;                            // 896 KB
    float* S  = (float*)p; p += (size_t)NB * NN * NN * 4;                            // 1 MB

    prep_weights<<<868, 256, 0, stream>>>(W1, W2, w1s, w2s);
    gather_embed<<<NB * NN, 256, 0, stream>>>(ee, eidx, emb);
    node_terms<<<NB * 32, 256, 0, stream>>>(emb, W1, An, Bn);
    pair_mlp<<<NB * TRI, 512, 0, stream>>>(emb, w1s, w2s, An, Bn, b1, b2, W3, b3, S);
    softmax_rows<<<NB * NN, 256, 0, stream>>>(S, out);
}

// Round 2
// 506.677 us; speedup vs baseline: 1.1009x; 1.1009x over previous
//
#include <hip/hip_runtime.h>

// ---------------------------------------------------------------------------
// CorefPairScorer: B=4, T=4096, D=768, N=256, HID=200 (padded to 224)
// h1(i,j) = relu(A[i] + Bv[j] + (emb_i*emb_j)@W1bot + b1)
// h2 = relu(h1@W2 + b2); s = h2@W3 + b3; masked softmax rows.
// R2: fixed VGPR spill (launch_bounds 512 -> 256 VGPRs), perm-based bf16
//     product pack, node terms via MFMA GEMM (emb @ [W1top|W1mid]).
// ---------------------------------------------------------------------------

#define NB 4
#define NN 256
#define DD 768
#define TT 4096
#define HP 224
#define NTILES 14
#define KT1 24
#define KT2 7
#define TRI 136
#define JSTR 776         // embJ LDS row stride (bf16): 2-way bank alias (free)
#define HSTR 232         // h1 LDS row stride (bf16): 2-way bank alias (free)
#define ABS 448          // AB row stride (bf16): [A(224) | B(224)]

typedef __attribute__((ext_vector_type(8))) short short8;
typedef __attribute__((ext_vector_type(4))) float f32x4;

union FragU { uint4 u; short8 s; };

__device__ __forceinline__ float bf2f(unsigned short x) {
    return __uint_as_float(((unsigned int)x) << 16);
}
__device__ __forceinline__ unsigned short f2bf(float f) {
    unsigned int u = __float_as_uint(f);
    u += 0x7fffu + ((u >> 16) & 1u);   // RNE
    return (unsigned short)(u >> 16);
}
__device__ __forceinline__ float blo(unsigned int v) { return __uint_as_float(v << 16); }
__device__ __forceinline__ float bhi(unsigned int v) { return __uint_as_float(v & 0xffff0000u); }
// packed bf16 pair: (a*b) with pre-unpacked b halves; truncating pack via v_perm
__device__ __forceinline__ unsigned int mulpack(unsigned int a, float bl, float bh) {
    unsigned int m0 = __float_as_uint(blo(a) * bl);
    unsigned int m1 = __float_as_uint(bhi(a) * bh);
    return __builtin_amdgcn_perm(m1, m0, 0x07060302u);
}

// ---------------------------------------------------------------------------
// K0: swizzle weights into MFMA B-fragment order (zero-padded cols/rows).
//   w1n: [W1top | W1mid] 768 x 448  (for node GEMM)
//   w1s: W1bot 768 x 224            (for pair phase 1)
//   w2s: W2   224 x 224             (for pair phase 2)
//   frag layout: buf[((kt*NT+nt)*64 + lane)*8 + j] = W[kt*32+(lane>>4)*8+j][nt*16+(lane&15)]
// ---------------------------------------------------------------------------
__global__ void prep_weights(const float* __restrict__ W1, const float* __restrict__ W2,
                             unsigned short* __restrict__ w1n,
                             unsigned short* __restrict__ w1s,
                             unsigned short* __restrict__ w2s) {
    int idx = blockIdx.x * 256 + threadIdx.x;
    const int N1n = 24 * 28 * 512;   // 344064
    const int N1s = 24 * 14 * 512;   // 172032
    const int N2  = 7 * 14 * 512;    // 50176
    if (idx < N1n) {
        int j = idx & 7, lane = (idx >> 3) & 63, f = idx >> 9;
        int nt = f % 28, kt = f / 28;
        int k = kt * 32 + (lane >> 4) * 8 + j;     // 0..767
        int n = nt * 16 + (lane & 15);             // 0..447
        float v;
        if (n < HP) v = (n < 200) ? W1[(size_t)k * 200 + n] : 0.f;
        else { int c2 = n - HP; v = (c2 < 200) ? W1[(size_t)(768 + k) * 200 + c2] : 0.f; }
        w1n[idx] = f2bf(v);
    } else if (idx < N1n + N1s) {
        int i2 = idx - N1n;
        int j = i2 & 7, lane = (i2 >> 3) & 63, f = i2 >> 9;
        int nt = f % NTILES, kt = f / NTILES;
        int k = kt * 32 + (lane >> 4) * 8 + j;
        int n = nt * 16 + (lane & 15);
        float v = (n < 200) ? W1[(size_t)(1536 + k) * 200 + n] : 0.f;
        w1s[i2] = f2bf(v);
    } else if (idx < N1n + N1s + N2) {
        int i2 = idx - N1n - N1s;
        int j = i2 & 7, lane = (i2 >> 3) & 63, f = i2 >> 9;
        int nt = f % NTILES, kt = f / NTILES;
        int k = kt * 32 + (lane >> 4) * 8 + j;
        int n = nt * 16 + (lane & 15);
        float v = (k < 200 && n < 200) ? W2[(size_t)k * 200 + n] : 0.f;
        w2s[i2] = f2bf(v);
    }
}

// ---------------------------------------------------------------------------
// K1: gather + fp32->bf16
// ---------------------------------------------------------------------------
__global__ void gather_embed(const float* __restrict__ ee, const int* __restrict__ eidx,
                             unsigned short* __restrict__ emb) {
    int b = blockIdx.x >> 8, n = blockIdx.x & 255;
    int t = eidx[b * NN + n];
    const float* src = ee + ((size_t)b * TT + t) * DD;
    unsigned short* dst = emb + ((size_t)b * NN + n) * DD;
    for (int e = threadIdx.x; e < DD; e += 256) dst[e] = f2bf(src[e]);
}

// ---------------------------------------------------------------------------
// K2: AB = emb(1024x768) @ [W1top|W1mid](768x448), bf16 MFMA, bf16 out.
//   32 blocks x 256 thr (4 waves). Block = 32 rows; wave: (mt = w>>1, ng = w&1).
// ---------------------------------------------------------------------------
__global__ __launch_bounds__(256) void node_mfma(const unsigned short* __restrict__ emb,
                                                 const unsigned short* __restrict__ w1n,
                                                 unsigned short* __restrict__ AB) {
    int tid = threadIdx.x, lane = tid & 63, w = tid >> 6;
    int q = lane >> 4, c = lane & 15;
    int mt = w >> 1, ng = w & 1;
    int m0 = blockIdx.x * 32 + mt * 16;
    const uint4* ga = (const uint4*)emb + (size_t)(m0 + c) * 96;
    const uint4* gb = (const uint4*)w1n;

    f32x4 acc[14];
#pragma unroll
    for (int n = 0; n < 14; ++n) acc[n] = (f32x4){0.f, 0.f, 0.f, 0.f};

    for (int kt = 0; kt < KT1; ++kt) {
        FragU a; a.u = ga[kt * 4 + q];
#pragma unroll
        for (int n = 0; n < 14; ++n) {
            FragU bb; bb.u = gb[((kt * 28 + ng * 14 + n) << 6) + lane];
            acc[n] = __builtin_amdgcn_mfma_f32_16x16x32_bf16(a.s, bb.s, acc[n], 0, 0, 0);
        }
    }
#pragma unroll
    for (int n = 0; n < 14; ++n) {
        int col = (ng * 14 + n) * 16 + c;
#pragma unroll
        for (int rr = 0; rr < 4; ++rr)
            AB[(size_t)(m0 + q * 4 + rr) * ABS + col] = f2bf(acc[n][rr]);
    }
}

// ---------------------------------------------------------------------------
// K3: fused pair MLP per 16x16 (i,j) tile. 512 threads = 8 waves.
// ---------------------------------------------------------------------------
__global__ __launch_bounds__(512) void pair_mlp(
    const unsigned short* __restrict__ emb,
    const unsigned short* __restrict__ w1s,
    const unsigned short* __restrict__ w2s,
    const unsigned short* __restrict__ AB,
    const float* __restrict__ b1, const float* __restrict__ b2,
    const float* __restrict__ W3, const float* __restrict__ b3,
    float* __restrict__ S) {
    int z = blockIdx.x;
    int b = z / TRI;
    int r = z % TRI;
    int ti = (int)((sqrtf(8.f * (float)r + 1.f) - 1.f) * 0.5f);
    while ((ti + 1) * (ti + 2) / 2 <= r) ++ti;
    while (ti * (ti + 1) / 2 > r) --ti;
    int tj = r - ti * (ti + 1) / 2;
    int i0 = ti << 4, j0 = tj << 4;

    int tid = threadIdx.x;
    int lane = tid & 63;
    int w = tid >> 6;
    int q = lane >> 4, c = lane & 15;
    int mg = w >> 1, nh = w & 1;

    __shared__ unsigned short sm[128 * HSTR];   // 59392 B (aliases embJ staging)
    __shared__ float sred[2][256];              // 2048 B

    // ---- stage embJ (16 rows x 768 bf16, stride 776) ----
    {
        const uint4* gJ = (const uint4*)(emb + ((size_t)b * NN + j0) * DD);
#pragma unroll
        for (int k = 0; k < 3; ++k) {
            int c2 = tid + 512 * k;
            int row = c2 / 96, col = c2 - row * 96;
            uint4 v = gJ[row * 96 + col];
            *(uint4*)(&sm[row * JSTR + col * 8]) = v;
        }
    }
    __syncthreads();

    f32x4 acc[4][7];
#pragma unroll
    for (int t = 0; t < 4; ++t)
#pragma unroll
        for (int n = 0; n < 7; ++n)
            acc[t][n] = (f32x4){0.f, 0.f, 0.f, 0.f};

    const uint4* w1f = (const uint4*)w1s;
    const uint4* gI = (const uint4*)(emb + ((size_t)b * NN + i0 + mg * 4) * DD);

    // ---- phase 1 K-loop: K=768, 24 ktiles ----
    for (int kt = 0; kt < KT1; ++kt) {
        uint4 bfr[7];
#pragma unroll
        for (int n = 0; n < 7; ++n)
            bfr[n] = w1f[(kt * NTILES + nh * 7 + n) * 64 + lane];
        uint4 ej = *(const uint4*)(&sm[c * JSTR + kt * 32 + q * 8]);
        float exl = blo(ej.x), exh = bhi(ej.x);
        float eyl = blo(ej.y), eyh = bhi(ej.y);
        float ezl = blo(ej.z), ezh = bhi(ej.z);
        float ewl = blo(ej.w), ewh = bhi(ej.w);
#pragma unroll
        for (int t = 0; t < 4; ++t) {
            uint4 ei = gI[t * 96 + kt * 4 + q];   // wave-quad broadcast (L1)
            FragU a;
            a.u.x = mulpack(ei.x, exl, exh);
            a.u.y = mulpack(ei.y, eyl, eyh);
            a.u.z = mulpack(ei.z, ezl, ezh);
            a.u.w = mulpack(ei.w, ewl, ewh);
#pragma unroll
            for (int n = 0; n < 7; ++n) {
                FragU bb; bb.u = bfr[n];
                acc[t][n] = __builtin_amdgcn_mfma_f32_16x16x32_bf16(a.s, bb.s, acc[t][n], 0, 0, 0);
            }
        }
    }

    // per-lane col constants for phase 2/3
    float b2v[7], w3v[7];
#pragma unroll
    for (int n = 0; n < 7; ++n) {
        int h = ((nh * 7 + n) << 4) + c;
        b2v[n] = (h < 200) ? b2[h] : 0.f;
        w3v[n] = (h < 200) ? W3[h] : 0.f;
    }
    float b3val = b3[0];
    const uint4* w2f = (const uint4*)w2s;

    for (int half = 0; half < 2; ++half) {
        __syncthreads();   // sm free for this half's h1
        if ((mg >> 1) == half) {
#pragma unroll
            for (int t = 0; t < 4; ++t) {
                int tg = (mg << 2) + t;                    // global Mtile (== ii)
                int lt16 = (tg - (half << 3)) << 4;        // local row base
#pragma unroll
                for (int n = 0; n < 7; ++n) {
                    int h = ((nh * 7 + n) << 4) + c;
                    float aI = bf2f(AB[(size_t)(b * NN + i0 + tg) * ABS + h]);
                    float base = aI + ((h < 200) ? b1[h] : 0.f);
#pragma unroll
                    for (int rr = 0; rr < 4; ++rr) {
                        float v = acc[t][n][rr] + base +
                                  bf2f(AB[(size_t)(b * NN + j0 + q * 4 + rr) * ABS + HP + h]);
                        v = fmaxf(v, 0.f);
                        sm[(lt16 + q * 4 + rr) * HSTR + h] = f2bf(v);
                    }
                }
            }
        }
        __syncthreads();

        // ---- phase 2: 128 pairs of this half, K=224 (7 ktiles) ----
        f32x4 acc2[2][7];
#pragma unroll
        for (int u = 0; u < 2; ++u)
#pragma unroll
            for (int n = 0; n < 7; ++n)
                acc2[u][n] = (f32x4){0.f, 0.f, 0.f, 0.f};

        for (int kk = 0; kk < KT2; ++kk) {
            uint4 bfr2[7];
#pragma unroll
            for (int n = 0; n < 7; ++n)
                bfr2[n] = w2f[(kk * NTILES + nh * 7 + n) * 64 + lane];
#pragma unroll
            for (int u = 0; u < 2; ++u) {
                int lt = mg * 2 + u;
                FragU a2;
                a2.u = *(const uint4*)(&sm[(lt * 16 + c) * HSTR + kk * 32 + q * 8]);
#pragma unroll
                for (int n = 0; n < 7; ++n) {
                    FragU bb; bb.u = bfr2[n];
                    acc2[u][n] = __builtin_amdgcn_mfma_f32_16x16x32_bf16(a2.s, bb.s, acc2[u][n], 0, 0, 0);
                }
            }
        }

        // ---- phase 3: s = relu(h2 + b2) . W3, reduce 16 cols via shfl ----
#pragma unroll
        for (int u = 0; u < 2; ++u) {
#pragma unroll
            for (int rr = 0; rr < 4; ++rr) {
                float part = 0.f;
#pragma unroll
                for (int n = 0; n < 7; ++n) {
                    float hv = fmaxf(acc2[u][n][rr] + b2v[n], 0.f);
                    part += hv * w3v[n];
                }
                part += __shfl_xor(part, 1);
                part += __shfl_xor(part, 2);
                part += __shfl_xor(part, 4);
                part += __shfl_xor(part, 8);
                if (c == 0) {
                    int p = (half << 7) + ((mg * 2 + u) << 4) + q * 4 + rr;
                    sred[nh][p] = part;
                }
            }
        }
    }
    __syncthreads();
    if (tid < 256) {
        int ii = tid >> 4, jj = tid & 15;
        float s = sred[0][tid] + sred[1][tid] + b3val;
        S[((size_t)b * NN + i0 + ii) * NN + j0 + jj] = s;
    }
}

// ---------------------------------------------------------------------------
// K4: masked softmax per row; diag logit = 0; invalid -> -1000
// ---------------------------------------------------------------------------
__global__ __launch_bounds__(256) void softmax_rows(const float* __restrict__ S,
                                                    float* __restrict__ out) {
    int b = blockIdx.x >> 8, i = blockIdx.x & 255;
    int j = threadIdx.x;
    int lane = j & 63, w = j >> 6;
    __shared__ float red[16];
    float x = (j < i) ? S[((size_t)b * NN + i) * NN + j] : ((j == i) ? 0.f : -1e30f);
    float m = x;
#pragma unroll
    for (int off = 32; off; off >>= 1) m = fmaxf(m, __shfl_xor(m, off));
    if (lane == 0) red[w] = m;
    __syncthreads();
    float mx = fmaxf(fmaxf(red[0], red[1]), fmaxf(red[2], red[3]));
    float e = (j <= i) ? __expf(x - mx) : 0.f;
    float s = e;
#pragma unroll
    for (int off = 32; off; off >>= 1) s += __shfl_xor(s, off);
    if (lane == 0) red[8 + w] = s;
    __syncthreads();
    float sum = red[8] + red[9] + red[10] + red[11];
    out[((size_t)b * NN + i) * NN + j] = (j <= i) ? (e / sum) : -1000.0f;
}

// ---------------------------------------------------------------------------
extern "C" void kernel_launch(void* const* d_in, const int* in_sizes, int n_in,
                              void* d_out, int out_size, void* d_ws, size_t ws_size,
                              hipStream_t stream) {
    const float* ee  = (const float*)d_in[0];
    const int*   eidx = (const int*)d_in[1];
    const float* W1  = (const float*)d_in[2];
    const float* b1  = (const float*)d_in[3];
    const float* W2  = (const float*)d_in[4];
    const float* b2  = (const float*)d_in[5];
    const float* W3  = (const float*)d_in[6];
    const float* b3  = (const float*)d_in[7];
    float* out = (float*)d_out;

    char* p = (char*)d_ws;
    unsigned short* emb = (unsigned short*)p; p += (size_t)NB * NN * DD * 2;       // 1.5 MB
    unsigned short* w1n = (unsigned short*)p; p += (size_t)24 * 28 * 512 * 2;      // 672 KB
    unsigned short* w1s = (unsigned short*)p; p += (size_t)24 * 14 * 512 * 2;      // 336 KB
    unsigned short* w2s = (unsigned short*)p; p += (size_t)7 * 14 * 512 * 2;       // 98 KB
    unsigned short* AB  = (unsigned short*)p; p += (size_t)NB * NN * ABS * 2;      // 896 KB
    float* S  = (float*)p; p += (size_t)NB * NN * NN * 4;                           // 1 MB

    prep_weights<<<2212, 256, 0, stream>>>(W1, W2, w1n, w1s, w2s);
    gather_embed<<<NB * NN, 256, 0, stream>>>(ee, eidx, emb);
    node_mfma<<<32, 256, 0, stream>>>(emb, w1n, AB);
    pair_mlp<<<NB * TRI, 512, 0, stream>>>(emb, w1s, w2s, AB, b1, b2, W3, b3, S);
    softmax_rows<<<NB * NN, 256, 0, stream>>>(S, out);
}

// Round 3
// 408.181 us; speedup vs baseline: 1.3666x; 1.2413x over previous
//
#include <hip/hip_runtime.h>

// ---------------------------------------------------------------------------
// CorefPairScorer: B=4, T=4096, D=768, N=256, HID=200 (padded to 224)
// h1(i,j) = relu(A[i] + Bv[j] + (emb_i*emb_j)@W1bot + b1)
// h2 = relu(h1@W2 + b2); s = h2@W3 + b3; masked softmax rows.
// R3: pair_mlp restructured into two sequential half-passes so phase-1 and
//     phase-2 accumulators are never live together (was: 168 AGPR demand vs
//     128 budget at 2 waves/EU -> 650 MB scratch spill traffic).
// ---------------------------------------------------------------------------

#define NB 4
#define NN 256
#define DD 768
#define TT 4096
#define HP 224
#define NTILES 14
#define KT1 24
#define KT2 7
#define TRI 136
#define JSTR 776         // embJ LDS row stride (shorts)
#define HSTR 232         // h1 LDS row stride (shorts)
#define ABS 448          // AB row stride (bf16): [A(224) | B(224)]

typedef __attribute__((ext_vector_type(8))) short short8;
typedef __attribute__((ext_vector_type(4))) float f32x4;

union FragU { uint4 u; short8 s; };

__device__ __forceinline__ float bf2f(unsigned short x) {
    return __uint_as_float(((unsigned int)x) << 16);
}
__device__ __forceinline__ unsigned short f2bf(float f) {
    unsigned int u = __float_as_uint(f);
    u += 0x7fffu + ((u >> 16) & 1u);   // RNE
    return (unsigned short)(u >> 16);
}
__device__ __forceinline__ float blo(unsigned int v) { return __uint_as_float(v << 16); }
__device__ __forceinline__ float bhi(unsigned int v) { return __uint_as_float(v & 0xffff0000u); }
// packed bf16 pair: (a*b) with pre-unpacked b halves; truncating pack via v_perm
__device__ __forceinline__ unsigned int mulpack(unsigned int a, float bl, float bh) {
    unsigned int m0 = __float_as_uint(blo(a) * bl);
    unsigned int m1 = __float_as_uint(bhi(a) * bh);
    return __builtin_amdgcn_perm(m1, m0, 0x07060302u);
}

// ---------------------------------------------------------------------------
// K0: swizzle weights into MFMA B-fragment order (zero-padded cols/rows).
// ---------------------------------------------------------------------------
__global__ void prep_weights(const float* __restrict__ W1, const float* __restrict__ W2,
                             unsigned short* __restrict__ w1n,
                             unsigned short* __restrict__ w1s,
                             unsigned short* __restrict__ w2s) {
    int idx = blockIdx.x * 256 + threadIdx.x;
    const int N1n = 24 * 28 * 512;   // 344064
    const int N1s = 24 * 14 * 512;   // 172032
    const int N2  = 7 * 14 * 512;    // 50176
    if (idx < N1n) {
        int j = idx & 7, lane = (idx >> 3) & 63, f = idx >> 9;
        int nt = f % 28, kt = f / 28;
        int k = kt * 32 + (lane >> 4) * 8 + j;     // 0..767
        int n = nt * 16 + (lane & 15);             // 0..447
        float v;
        if (n < HP) v = (n < 200) ? W1[(size_t)k * 200 + n] : 0.f;
        else { int c2 = n - HP; v = (c2 < 200) ? W1[(size_t)(768 + k) * 200 + c2] : 0.f; }
        w1n[idx] = f2bf(v);
    } else if (idx < N1n + N1s) {
        int i2 = idx - N1n;
        int j = i2 & 7, lane = (i2 >> 3) & 63, f = i2 >> 9;
        int nt = f % NTILES, kt = f / NTILES;
        int k = kt * 32 + (lane >> 4) * 8 + j;
        int n = nt * 16 + (lane & 15);
        float v = (n < 200) ? W1[(size_t)(1536 + k) * 200 + n] : 0.f;
        w1s[i2] = f2bf(v);
    } else if (idx < N1n + N1s + N2) {
        int i2 = idx - N1n - N1s;
        int j = i2 & 7, lane = (i2 >> 3) & 63, f = i2 >> 9;
        int nt = f % NTILES, kt = f / NTILES;
        int k = kt * 32 + (lane >> 4) * 8 + j;
        int n = nt * 16 + (lane & 15);
        float v = (k < 200 && n < 200) ? W2[(size_t)k * 200 + n] : 0.f;
        w2s[i2] = f2bf(v);
    }
}

// ---------------------------------------------------------------------------
// K1: gather + fp32->bf16
// ---------------------------------------------------------------------------
__global__ void gather_embed(const float* __restrict__ ee, const int* __restrict__ eidx,
                             unsigned short* __restrict__ emb) {
    int b = blockIdx.x >> 8, n = blockIdx.x & 255;
    int t = eidx[b * NN + n];
    const float* src = ee + ((size_t)b * TT + t) * DD;
    unsigned short* dst = emb + ((size_t)b * NN + n) * DD;
    for (int e = threadIdx.x; e < DD; e += 256) dst[e] = f2bf(src[e]);
}

// ---------------------------------------------------------------------------
// K2: AB = emb(1024x768) @ [W1top|W1mid](768x448), bf16 MFMA, bf16 out.
// ---------------------------------------------------------------------------
__global__ __launch_bounds__(256) void node_mfma(const unsigned short* __restrict__ emb,
                                                 const unsigned short* __restrict__ w1n,
                                                 unsigned short* __restrict__ AB) {
    int tid = threadIdx.x, lane = tid & 63, w = tid >> 6;
    int q = lane >> 4, c = lane & 15;
    int mt = w >> 1, ng = w & 1;
    int m0 = blockIdx.x * 32 + mt * 16;
    const uint4* ga = (const uint4*)emb + (size_t)(m0 + c) * 96;
    const uint4* gb = (const uint4*)w1n;

    f32x4 acc[14];
#pragma unroll
    for (int n = 0; n < 14; ++n) acc[n] = (f32x4){0.f, 0.f, 0.f, 0.f};

    for (int kt = 0; kt < KT1; ++kt) {
        FragU a; a.u = ga[kt * 4 + q];
#pragma unroll
        for (int n = 0; n < 14; ++n) {
            FragU bb; bb.u = gb[((kt * 28 + ng * 14 + n) << 6) + lane];
            acc[n] = __builtin_amdgcn_mfma_f32_16x16x32_bf16(a.s, bb.s, acc[n], 0, 0, 0);
        }
    }
#pragma unroll
    for (int n = 0; n < 14; ++n) {
        int col = (ng * 14 + n) * 16 + c;
#pragma unroll
        for (int rr = 0; rr < 4; ++rr)
            AB[(size_t)(m0 + q * 4 + rr) * ABS + col] = f2bf(acc[n][rr]);
    }
}

// ---------------------------------------------------------------------------
// K3: fused pair MLP per 16x16 (i,j) tile. 512 threads = 8 waves.
//   Two sequential half-passes (rows 0..127 then 128..255 of the 256-pair
//   tile). Per pass: phase1 acc[2][7] (56 AGPR) -> epilogue -> h1 in LDS
//   (aliases embJ staging) -> phase2 acc2[2][7] -> phase3 reduce.
//   No acc/acc2 liveness overlap => no spill at 2 waves/EU (256-reg budget).
// ---------------------------------------------------------------------------
__global__ __launch_bounds__(512) void pair_mlp(
    const unsigned short* __restrict__ emb,
    const unsigned short* __restrict__ w1s,
    const unsigned short* __restrict__ w2s,
    const unsigned short* __restrict__ AB,
    const float* __restrict__ b1, const float* __restrict__ b2,
    const float* __restrict__ W3, const float* __restrict__ b3,
    float* __restrict__ S) {
    int z = blockIdx.x;
    int b = z / TRI;
    int r = z % TRI;
    int ti = (int)((sqrtf(8.f * (float)r + 1.f) - 1.f) * 0.5f);
    while ((ti + 1) * (ti + 2) / 2 <= r) ++ti;
    while (ti * (ti + 1) / 2 > r) --ti;
    int tj = r - ti * (ti + 1) / 2;
    int i0 = ti << 4, j0 = tj << 4;

    int tid = threadIdx.x;
    int lane = tid & 63;
    int w = tid >> 6;
    int q = lane >> 4, c = lane & 15;
    int mg = w >> 1, nh = w & 1;          // mg 0..3, nh 0..1

    __shared__ unsigned short sm[128 * HSTR];   // 59392 B; embJ (16*776) aliases
    __shared__ float sred[2][256];              // 2048 B

    const uint4* w1f = (const uint4*)w1s;
    const uint4* w2f = (const uint4*)w2s;
    const uint4* gI  = (const uint4*)(emb + ((size_t)b * NN + i0) * DD);
    const uint4* gJ  = (const uint4*)(emb + ((size_t)b * NN + j0) * DD);

    // per-lane col constants for phase 2/3
    float b2v[7], w3v[7];
#pragma unroll
    for (int n = 0; n < 7; ++n) {
        int h = ((nh * 7 + n) << 4) + c;
        b2v[n] = (h < 200) ? b2[h] : 0.f;
        w3v[n] = (h < 200) ? W3[h] : 0.f;
    }
    float b3val = b3[0];

    for (int half = 0; half < 2; ++half) {
        // ---- stage embJ (16 rows x 768 bf16, stride 776) ----
        __syncthreads();   // sm free (prev phase2 done / first iter no-op)
#pragma unroll
        for (int k = 0; k < 3; ++k) {
            int c2 = tid + 512 * k;
            int row = c2 / 96, col = c2 - row * 96;
            uint4 v = gJ[row * 96 + col];
            *(uint4*)(&sm[row * JSTR + col * 8]) = v;
        }
        __syncthreads();

        // ---- phase 1: this half's 8 Mtiles; wave does Mtiles 2mg,2mg+1 ----
        f32x4 acc[2][7];
#pragma unroll
        for (int t = 0; t < 2; ++t)
#pragma unroll
            for (int n = 0; n < 7; ++n)
                acc[t][n] = (f32x4){0.f, 0.f, 0.f, 0.f};

        for (int kt = 0; kt < KT1; ++kt) {
            uint4 bfr[7];
#pragma unroll
            for (int n = 0; n < 7; ++n)
                bfr[n] = w1f[(kt * NTILES + nh * 7 + n) * 64 + lane];
            uint4 ej = *(const uint4*)(&sm[c * JSTR + kt * 32 + q * 8]);
            float exl = blo(ej.x), exh = bhi(ej.x);
            float eyl = blo(ej.y), eyh = bhi(ej.y);
            float ezl = blo(ej.z), ezh = bhi(ej.z);
            float ewl = blo(ej.w), ewh = bhi(ej.w);
#pragma unroll
            for (int t = 0; t < 2; ++t) {
                int tg = (half << 3) + (mg << 1) + t;   // global Mtile == i offset
                uint4 ei = gI[tg * 96 + kt * 4 + q];    // quad-broadcast (L1)
                FragU a;
                a.u.x = mulpack(ei.x, exl, exh);
                a.u.y = mulpack(ei.y, eyl, eyh);
                a.u.z = mulpack(ei.z, ezl, ezh);
                a.u.w = mulpack(ei.w, ewl, ewh);
#pragma unroll
                for (int n = 0; n < 7; ++n) {
                    FragU bb; bb.u = bfr[n];
                    acc[t][n] = __builtin_amdgcn_mfma_f32_16x16x32_bf16(a.s, bb.s, acc[t][n], 0, 0, 0);
                }
            }
        }

        // ---- epilogue: h1 = relu(acc + A[i] + Bv[j] + b1) -> LDS bf16 ----
        __syncthreads();   // all waves done reading embJ region
#pragma unroll
        for (int t = 0; t < 2; ++t) {
            int tg = (half << 3) + (mg << 1) + t;
            int lt16 = ((mg << 1) + t) << 4;            // local row base in half
#pragma unroll
            for (int n = 0; n < 7; ++n) {
                int h = ((nh * 7 + n) << 4) + c;
                float aI = bf2f(AB[(size_t)(b * NN + i0 + tg) * ABS + h]);
                float base = aI + ((h < 200) ? b1[h] : 0.f);
#pragma unroll
                for (int rr = 0; rr < 4; ++rr) {
                    float v = acc[t][n][rr] + base +
                              bf2f(AB[(size_t)(b * NN + j0 + q * 4 + rr) * ABS + HP + h]);
                    v = fmaxf(v, 0.f);
                    sm[(lt16 + q * 4 + rr) * HSTR + h] = f2bf(v);
                }
            }
        }
        __syncthreads();

        // ---- phase 2: 128 pairs of this half, K=224 (7 ktiles) ----
        f32x4 acc2[2][7];
#pragma unroll
        for (int u = 0; u < 2; ++u)
#pragma unroll
            for (int n = 0; n < 7; ++n)
                acc2[u][n] = (f32x4){0.f, 0.f, 0.f, 0.f};

        for (int kk = 0; kk < KT2; ++kk) {
            uint4 bfr2[7];
#pragma unroll
            for (int n = 0; n < 7; ++n)
                bfr2[n] = w2f[(kk * NTILES + nh * 7 + n) * 64 + lane];
#pragma unroll
            for (int u = 0; u < 2; ++u) {
                int lt = (mg << 1) + u;   // 0..7
                FragU a2;
                a2.u = *(const uint4*)(&sm[(lt * 16 + c) * HSTR + kk * 32 + q * 8]);
#pragma unroll
                for (int n = 0; n < 7; ++n) {
                    FragU bb; bb.u = bfr2[n];
                    acc2[u][n] = __builtin_amdgcn_mfma_f32_16x16x32_bf16(a2.s, bb.s, acc2[u][n], 0, 0, 0);
                }
            }
        }

        // ---- phase 3: s = relu(h2 + b2) . W3, reduce 16 cols via shfl ----
#pragma unroll
        for (int u = 0; u < 2; ++u) {
#pragma unroll
            for (int rr = 0; rr < 4; ++rr) {
                float part = 0.f;
#pragma unroll
                for (int n = 0; n < 7; ++n) {
                    float hv = fmaxf(acc2[u][n][rr] + b2v[n], 0.f);
                    part += hv * w3v[n];
                }
                part += __shfl_xor(part, 1);
                part += __shfl_xor(part, 2);
                part += __shfl_xor(part, 4);
                part += __shfl_xor(part, 8);
                if (c == 0) {
                    int p = (half << 7) + (((mg << 1) + u) << 4) + q * 4 + rr;
                    sred[nh][p] = part;
                }
            }
        }
    }
    __syncthreads();
    if (tid < 256) {
        int ii = tid >> 4, jj = tid & 15;
        float s = sred[0][tid] + sred[1][tid] + b3val;
        S[((size_t)b * NN + i0 + ii) * NN + j0 + jj] = s;
    }
}

// ---------------------------------------------------------------------------
// K4: masked softmax per row; diag logit = 0; invalid -> -1000
// ---------------------------------------------------------------------------
__global__ __launch_bounds__(256) void softmax_rows(const float* __restrict__ S,
                                                    float* __restrict__ out) {
    int b = blockIdx.x >> 8, i = blockIdx.x & 255;
    int j = threadIdx.x;
    int lane = j & 63, w = j >> 6;
    __shared__ float red[16];
    float x = (j < i) ? S[((size_t)b * NN + i) * NN + j] : ((j == i) ? 0.f : -1e30f);
    float m = x;
#pragma unroll
    for (int off = 32; off; off >>= 1) m = fmaxf(m, __shfl_xor(m, off));
    if (lane == 0) red[w] = m;
    __syncthreads();
    float mx = fmaxf(fmaxf(red[0], red[1]), fmaxf(red[2], red[3]));
    float e = (j <= i) ? __expf(x - mx) : 0.f;
    float s = e;
#pragma unroll
    for (int off = 32; off; off >>= 1) s += __shfl_xor(s, off);
    if (lane == 0) red[8 + w] = s;
    __syncthreads();
    float sum = red[8] + red[9] + red[10] + red[11];
    out[((size_t)b * NN + i) * NN + j] = (j <= i) ? (e / sum) : -1000.0f;
}

// ---------------------------------------------------------------------------
extern "C" void kernel_launch(void* const* d_in, const int* in_sizes, int n_in,
                              void* d_out, int out_size, void* d_ws, size_t ws_size,
                              hipStream_t stream) {
    const float* ee  = (const float*)d_in[0];
    const int*   eidx = (const int*)d_in[1];
    const float* W1  = (const float*)d_in[2];
    const float* b1  = (const float*)d_in[3];
    const float* W2  = (const float*)d_in[4];
    const float* b2  = (const float*)d_in[5];
    const float* W3  = (const float*)d_in[6];
    const float* b3  = (const float*)d_in[7];
    float* out = (float*)d_out;

    char* p = (char*)d_ws;
    unsigned short* emb = (unsigned short*)p; p += (size_t)NB * NN * DD * 2;       // 1.5 MB
    unsigned short* w1n = (unsigned short*)p; p += (size_t)24 * 28 * 512 * 2;      // 672 KB
    unsigned short* w1s = (unsigned short*)p; p += (size_t)24 * 14 * 512 * 2;      // 336 KB
    unsigned short* w2s = (unsigned short*)p; p += (size_t)7 * 14 * 512 * 2;       // 98 KB
    unsigned short* AB  = (unsigned short*)p; p += (size_t)NB * NN * ABS * 2;      // 896 KB
    float* S  = (float*)p; p += (size_t)NB * NN * NN * 4;                           // 1 MB

    prep_weights<<<2212, 256, 0, stream>>>(W1, W2, w1n, w1s, w2s);
    gather_embed<<<NB * NN, 256, 0, stream>>>(ee, eidx, emb);
    node_mfma<<<32, 256, 0, stream>>>(emb, w1n, AB);
    pair_mlp<<<NB * TRI, 512, 0, stream>>>(emb, w1s, w2s, AB, b1, b2, W3, b3, S);
    softmax_rows<<<NB * NN, 256, 0, stream>>>(S, out);
}

// Round 4
// 340.109 us; speedup vs baseline: 1.6401x; 1.2001x over previous
//
#include <hip/hip_runtime.h>

// ---------------------------------------------------------------------------
// CorefPairScorer: B=4, T=4096, D=768, N=256, HID=200 (padded to 224)
// h1(i,j) = relu(A[i] + Bv[j] + (emb_i*emb_j)@W1bot + b1)
// h2 = relu(h1@W2 + b2); s = h2@W3 + b3; masked softmax rows.
// R4: force register budget with amdgpu_waves_per_eu(1,2) — compiler was
//     pinning 128 regs/wave (4 waves/EU target) irrespective of
//     __launch_bounds__, spilling the K-loop working set (~320 MB scratch
//     traffic). Demand ~180 regs; 2 waves/EU runtime occupancy unchanged
//     (LDS 60KB caps at 2 blocks/CU anyway).
// ---------------------------------------------------------------------------

#define NB 4
#define NN 256
#define DD 768
#define TT 4096
#define HP 224
#define NTILES 14
#define KT1 24
#define KT2 7
#define TRI 136
#define JSTR 776         // embJ LDS row stride (shorts)
#define HSTR 232         // h1 LDS row stride (shorts)
#define ABS 448          // AB row stride (bf16): [A(224) | B(224)]

typedef __attribute__((ext_vector_type(8))) short short8;
typedef __attribute__((ext_vector_type(4))) float f32x4;

union FragU { uint4 u; short8 s; };

__device__ __forceinline__ float bf2f(unsigned short x) {
    return __uint_as_float(((unsigned int)x) << 16);
}
__device__ __forceinline__ unsigned short f2bf(float f) {
    unsigned int u = __float_as_uint(f);
    u += 0x7fffu + ((u >> 16) & 1u);   // RNE
    return (unsigned short)(u >> 16);
}
__device__ __forceinline__ float blo(unsigned int v) { return __uint_as_float(v << 16); }
__device__ __forceinline__ float bhi(unsigned int v) { return __uint_as_float(v & 0xffff0000u); }
// packed bf16 pair: (a*b) with pre-unpacked b halves; truncating pack via v_perm
__device__ __forceinline__ unsigned int mulpack(unsigned int a, float bl, float bh) {
    unsigned int m0 = __float_as_uint(blo(a) * bl);
    unsigned int m1 = __float_as_uint(bhi(a) * bh);
    return __builtin_amdgcn_perm(m1, m0, 0x07060302u);
}

// ---------------------------------------------------------------------------
// K0: swizzle weights into MFMA B-fragment order (zero-padded cols/rows).
// ---------------------------------------------------------------------------
__global__ void prep_weights(const float* __restrict__ W1, const float* __restrict__ W2,
                             unsigned short* __restrict__ w1n,
                             unsigned short* __restrict__ w1s,
                             unsigned short* __restrict__ w2s) {
    int idx = blockIdx.x * 256 + threadIdx.x;
    const int N1n = 24 * 28 * 512;   // 344064
    const int N1s = 24 * 14 * 512;   // 172032
    const int N2  = 7 * 14 * 512;    // 50176
    if (idx < N1n) {
        int j = idx & 7, lane = (idx >> 3) & 63, f = idx >> 9;
        int nt = f % 28, kt = f / 28;
        int k = kt * 32 + (lane >> 4) * 8 + j;     // 0..767
        int n = nt * 16 + (lane & 15);             // 0..447
        float v;
        if (n < HP) v = (n < 200) ? W1[(size_t)k * 200 + n] : 0.f;
        else { int c2 = n - HP; v = (c2 < 200) ? W1[(size_t)(768 + k) * 200 + c2] : 0.f; }
        w1n[idx] = f2bf(v);
    } else if (idx < N1n + N1s) {
        int i2 = idx - N1n;
        int j = i2 & 7, lane = (i2 >> 3) & 63, f = i2 >> 9;
        int nt = f % NTILES, kt = f / NTILES;
        int k = kt * 32 + (lane >> 4) * 8 + j;
        int n = nt * 16 + (lane & 15);
        float v = (n < 200) ? W1[(size_t)(1536 + k) * 200 + n] : 0.f;
        w1s[i2] = f2bf(v);
    } else if (idx < N1n + N1s + N2) {
        int i2 = idx - N1n - N1s;
        int j = i2 & 7, lane = (i2 >> 3) & 63, f = i2 >> 9;
        int nt = f % NTILES, kt = f / NTILES;
        int k = kt * 32 + (lane >> 4) * 8 + j;
        int n = nt * 16 + (lane & 15);
        float v = (k < 200 && n < 200) ? W2[(size_t)k * 200 + n] : 0.f;
        w2s[i2] = f2bf(v);
    }
}

// ---------------------------------------------------------------------------
// K1: gather + fp32->bf16
// ---------------------------------------------------------------------------
__global__ void gather_embed(const float* __restrict__ ee, const int* __restrict__ eidx,
                             unsigned short* __restrict__ emb) {
    int b = blockIdx.x >> 8, n = blockIdx.x & 255;
    int t = eidx[b * NN + n];
    const float* src = ee + ((size_t)b * TT + t) * DD;
    unsigned short* dst = emb + ((size_t)b * NN + n) * DD;
    for (int e = threadIdx.x; e < DD; e += 256) dst[e] = f2bf(src[e]);
}

// ---------------------------------------------------------------------------
// K2: AB = emb(1024x768) @ [W1top|W1mid](768x448), bf16 MFMA, bf16 out.
// ---------------------------------------------------------------------------
__global__ __launch_bounds__(256) __attribute__((amdgpu_waves_per_eu(1, 2)))
void node_mfma(const unsigned short* __restrict__ emb,
               const unsigned short* __restrict__ w1n,
               unsigned short* __restrict__ AB) {
    int tid = threadIdx.x, lane = tid & 63, w = tid >> 6;
    int q = lane >> 4, c = lane & 15;
    int mt = w >> 1, ng = w & 1;
    int m0 = blockIdx.x * 32 + mt * 16;
    const uint4* ga = (const uint4*)emb + (size_t)(m0 + c) * 96;
    const uint4* gb = (const uint4*)w1n;

    f32x4 acc[14];
#pragma unroll
    for (int n = 0; n < 14; ++n) acc[n] = (f32x4){0.f, 0.f, 0.f, 0.f};

    for (int kt = 0; kt < KT1; ++kt) {
        FragU a; a.u = ga[kt * 4 + q];
#pragma unroll
        for (int n = 0; n < 14; ++n) {
            FragU bb; bb.u = gb[((kt * 28 + ng * 14 + n) << 6) + lane];
            acc[n] = __builtin_amdgcn_mfma_f32_16x16x32_bf16(a.s, bb.s, acc[n], 0, 0, 0);
        }
    }
#pragma unroll
    for (int n = 0; n < 14; ++n) {
        int col = (ng * 14 + n) * 16 + c;
#pragma unroll
        for (int rr = 0; rr < 4; ++rr)
            AB[(size_t)(m0 + q * 4 + rr) * ABS + col] = f2bf(acc[n][rr]);
    }
}

// ---------------------------------------------------------------------------
// K3: fused pair MLP per 16x16 (i,j) tile. 512 threads = 8 waves.
//   Two sequential half-passes; phase1 acc and phase2 acc2 never co-live.
// ---------------------------------------------------------------------------
__global__ __launch_bounds__(512) __attribute__((amdgpu_waves_per_eu(1, 2)))
void pair_mlp(
    const unsigned short* __restrict__ emb,
    const unsigned short* __restrict__ w1s,
    const unsigned short* __restrict__ w2s,
    const unsigned short* __restrict__ AB,
    const float* __restrict__ b1, const float* __restrict__ b2,
    const float* __restrict__ W3, const float* __restrict__ b3,
    float* __restrict__ S) {
    int z = blockIdx.x;
    int b = z / TRI;
    int r = z % TRI;
    int ti = (int)((sqrtf(8.f * (float)r + 1.f) - 1.f) * 0.5f);
    while ((ti + 1) * (ti + 2) / 2 <= r) ++ti;
    while (ti * (ti + 1) / 2 > r) --ti;
    int tj = r - ti * (ti + 1) / 2;
    int i0 = ti << 4, j0 = tj << 4;

    int tid = threadIdx.x;
    int lane = tid & 63;
    int w = tid >> 6;
    int q = lane >> 4, c = lane & 15;
    int mg = w >> 1, nh = w & 1;          // mg 0..3, nh 0..1

    __shared__ unsigned short sm[128 * HSTR];   // 59392 B; embJ (16*776) aliases
    __shared__ float sred[2][256];              // 2048 B

    const uint4* w1f = (const uint4*)w1s;
    const uint4* w2f = (const uint4*)w2s;
    const uint4* gI  = (const uint4*)(emb + ((size_t)b * NN + i0) * DD);
    const uint4* gJ  = (const uint4*)(emb + ((size_t)b * NN + j0) * DD);

    // per-lane col constants for phase 2/3
    float b2v[7], w3v[7];
#pragma unroll
    for (int n = 0; n < 7; ++n) {
        int h = ((nh * 7 + n) << 4) + c;
        b2v[n] = (h < 200) ? b2[h] : 0.f;
        w3v[n] = (h < 200) ? W3[h] : 0.f;
    }
    float b3val = b3[0];

    for (int half = 0; half < 2; ++half) {
        // ---- stage embJ (16 rows x 768 bf16, stride 776) ----
        __syncthreads();   // sm free (prev phase2 done / first iter no-op)
#pragma unroll
        for (int k = 0; k < 3; ++k) {
            int c2 = tid + 512 * k;
            int row = c2 / 96, col = c2 - row * 96;
            uint4 v = gJ[row * 96 + col];
            *(uint4*)(&sm[row * JSTR + col * 8]) = v;
        }
        __syncthreads();

        // ---- phase 1: this half's 8 Mtiles; wave does Mtiles 2mg,2mg+1 ----
        f32x4 acc[2][7];
#pragma unroll
        for (int t = 0; t < 2; ++t)
#pragma unroll
            for (int n = 0; n < 7; ++n)
                acc[t][n] = (f32x4){0.f, 0.f, 0.f, 0.f};

        for (int kt = 0; kt < KT1; ++kt) {
            uint4 bfr[7];
#pragma unroll
            for (int n = 0; n < 7; ++n)
                bfr[n] = w1f[(kt * NTILES + nh * 7 + n) * 64 + lane];
            uint4 ej = *(const uint4*)(&sm[c * JSTR + kt * 32 + q * 8]);
            float exl = blo(ej.x), exh = bhi(ej.x);
            float eyl = blo(ej.y), eyh = bhi(ej.y);
            float ezl = blo(ej.z), ezh = bhi(ej.z);
            float ewl = blo(ej.w), ewh = bhi(ej.w);
#pragma unroll
            for (int t = 0; t < 2; ++t) {
                int tg = (half << 3) + (mg << 1) + t;   // global Mtile == i offset
                uint4 ei = gI[tg * 96 + kt * 4 + q];    // quad-broadcast (L1)
                FragU a;
                a.u.x = mulpack(ei.x, exl, exh);
                a.u.y = mulpack(ei.y, eyl, eyh);
                a.u.z = mulpack(ei.z, ezl, ezh);
                a.u.w = mulpack(ei.w, ewl, ewh);
#pragma unroll
                for (int n = 0; n < 7; ++n) {
                    FragU bb; bb.u = bfr[n];
                    acc[t][n] = __builtin_amdgcn_mfma_f32_16x16x32_bf16(a.s, bb.s, acc[t][n], 0, 0, 0);
                }
            }
        }

        // ---- epilogue: h1 = relu(acc + A[i] + Bv[j] + b1) -> LDS bf16 ----
        __syncthreads();   // all waves done reading embJ region
#pragma unroll
        for (int t = 0; t < 2; ++t) {
            int tg = (half << 3) + (mg << 1) + t;
            int lt16 = ((mg << 1) + t) << 4;            // local row base in half
#pragma unroll
            for (int n = 0; n < 7; ++n) {
                int h = ((nh * 7 + n) << 4) + c;
                float aI = bf2f(AB[(size_t)(b * NN + i0 + tg) * ABS + h]);
                float base = aI + ((h < 200) ? b1[h] : 0.f);
#pragma unroll
                for (int rr = 0; rr < 4; ++rr) {
                    float v = acc[t][n][rr] + base +
                              bf2f(AB[(size_t)(b * NN + j0 + q * 4 + rr) * ABS + HP + h]);
                    v = fmaxf(v, 0.f);
                    sm[(lt16 + q * 4 + rr) * HSTR + h] = f2bf(v);
                }
            }
        }
        __syncthreads();

        // ---- phase 2: 128 pairs of this half, K=224 (7 ktiles) ----
        f32x4 acc2[2][7];
#pragma unroll
        for (int u = 0; u < 2; ++u)
#pragma unroll
            for (int n = 0; n < 7; ++n)
                acc2[u][n] = (f32x4){0.f, 0.f, 0.f, 0.f};

        for (int kk = 0; kk < KT2; ++kk) {
            uint4 bfr2[7];
#pragma unroll
            for (int n = 0; n < 7; ++n)
                bfr2[n] = w2f[(kk * NTILES + nh * 7 + n) * 64 + lane];
#pragma unroll
            for (int u = 0; u < 2; ++u) {
                int lt = (mg << 1) + u;   // 0..7
                FragU a2;
                a2.u = *(const uint4*)(&sm[(lt * 16 + c) * HSTR + kk * 32 + q * 8]);
#pragma unroll
                for (int n = 0; n < 7; ++n) {
                    FragU bb; bb.u = bfr2[n];
                    acc2[u][n] = __builtin_amdgcn_mfma_f32_16x16x32_bf16(a2.s, bb.s, acc2[u][n], 0, 0, 0);
                }
            }
        }

        // ---- phase 3: s = relu(h2 + b2) . W3, reduce 16 cols via shfl ----
#pragma unroll
        for (int u = 0; u < 2; ++u) {
#pragma unroll
            for (int rr = 0; rr < 4; ++rr) {
                float part = 0.f;
#pragma unroll
                for (int n = 0; n < 7; ++n) {
                    float hv = fmaxf(acc2[u][n][rr] + b2v[n], 0.f);
                    part += hv * w3v[n];
                }
                part += __shfl_xor(part, 1);
                part += __shfl_xor(part, 2);
                part += __shfl_xor(part, 4);
                part += __shfl_xor(part, 8);
                if (c == 0) {
                    int p = (half << 7) + (((mg << 1) + u) << 4) + q * 4 + rr;
                    sred[nh][p] = part;
                }
            }
        }
    }
    __syncthreads();
    if (tid < 256) {
        int ii = tid >> 4, jj = tid & 15;
        float s = sred[0][tid] + sred[1][tid] + b3val;
        S[((size_t)b * NN + i0 + ii) * NN + j0 + jj] = s;
    }
}

// ---------------------------------------------------------------------------
// K4: masked softmax per row; diag logit = 0; invalid -> -1000
// ---------------------------------------------------------------------------
__global__ __launch_bounds__(256) void softmax_rows(const float* __restrict__ S,
                                                    float* __restrict__ out) {
    int b = blockIdx.x >> 8, i = blockIdx.x & 255;
    int j = threadIdx.x;
    int lane = j & 63, w = j >> 6;
    __shared__ float red[16];
    float x = (j < i) ? S[((size_t)b * NN + i) * NN + j] : ((j == i) ? 0.f : -1e30f);
    float m = x;
#pragma unroll
    for (int off = 32; off; off >>= 1) m = fmaxf(m, __shfl_xor(m, off));
    if (lane == 0) red[w] = m;
    __syncthreads();
    float mx = fmaxf(fmaxf(red[0], red[1]), fmaxf(red[2], red[3]));
    float e = (j <= i) ? __expf(x - mx) : 0.f;
    float s = e;
#pragma unroll
    for (int off = 32; off; off >>= 1) s += __shfl_xor(s, off);
    if (lane == 0) red[8 + w] = s;
    __syncthreads();
    float sum = red[8] + red[9] + red[10] + red[11];
    out[((size_t)b * NN + i) * NN + j] = (j <= i) ? (e / sum) : -1000.0f;
}

// ---------------------------------------------------------------------------
extern "C" void kernel_launch(void* const* d_in, const int* in_sizes, int n_in,
                              void* d_out, int out_size, void* d_ws, size_t ws_size,
                              hipStream_t stream) {
    const float* ee  = (const float*)d_in[0];
    const int*   eidx = (const int*)d_in[1];
    const float* W1  = (const float*)d_in[2];
    const float* b1  = (const float*)d_in[3];
    const float* W2  = (const float*)d_in[4];
    const float* b2  = (const float*)d_in[5];
    const float* W3  = (const float*)d_in[6];
    const float* b3  = (const float*)d_in[7];
    float* out = (float*)d_out;

    char* p = (char*)d_ws;
    unsigned short* emb = (unsigned short*)p; p += (size_t)NB * NN * DD * 2;       // 1.5 MB
    unsigned short* w1n = (unsigned short*)p; p += (size_t)24 * 28 * 512 * 2;      // 672 KB
    unsigned short* w1s = (unsigned short*)p; p += (size_t)24 * 14 * 512 * 2;      // 336 KB
    unsigned short* w2s = (unsigned short*)p; p += (size_t)7 * 14 * 512 * 2;       // 98 KB
    unsigned short* AB  = (unsigned short*)p; p += (size_t)NB * NN * ABS * 2;      // 896 KB
    float* S  = (float*)p; p += (size_t)NB * NN * NN * 4;                           // 1 MB

    prep_weights<<<2212, 256, 0, stream>>>(W1, W2, w1n, w1s, w2s);
    gather_embed<<<NB * NN, 256, 0, stream>>>(ee, eidx, emb);
    node_mfma<<<32, 256, 0, stream>>>(emb, w1n, AB);
    pair_mlp<<<NB * TRI, 512, 0, stream>>>(emb, w1s, w2s, AB, b1, b2, W3, b3, S);
    softmax_rows<<<NB * NN, 256, 0, stream>>>(S, out);
}